// Round 3
// baseline (928.041 us; speedup 1.0000x reference)
//
#include <hip/hip_runtime.h>
#include <hip/hip_bf16.h>

typedef __bf16 bf16_t;
typedef __bf16 bf16x4 __attribute__((ext_vector_type(4)));
typedef __bf16 bf16x8 __attribute__((ext_vector_type(8)));
typedef float f32x4 __attribute__((ext_vector_type(4)));

#define MFMA16(a, b, c) __builtin_amdgcn_mfma_f32_16x16x32_bf16((a), (b), (c), 0, 0, 0)

__device__ inline void g2l16(const void* g, void* l) {
    __builtin_amdgcn_global_load_lds((const __attribute__((address_space(1))) void*)g,
                                     (__attribute__((address_space(3))) void*)l, 16, 0, 0);
}

// ---------------- fp32 -> bf16 conversion (vectorized) ----------------
__global__ __launch_bounds__(256) void cvt_f32_bf16_k(const float* __restrict__ src,
                                                      bf16_t* __restrict__ dst, int n4) {
    int i = blockIdx.x * 256 + threadIdx.x;
    if (i < n4) {
        float4 v = reinterpret_cast<const float4*>(src)[i];
        bf16x4 o;
        o[0] = (__bf16)v.x; o[1] = (__bf16)v.y; o[2] = (__bf16)v.z; o[3] = (__bf16)v.w;
        reinterpret_cast<bf16x4*>(dst)[i] = o;
    }
}

// ---------------- fp32 -> (hi, lo) bf16 pair split ----------------
__global__ __launch_bounds__(256) void cvt_split_k(const float* __restrict__ src,
                                                   bf16_t* __restrict__ hi,
                                                   bf16_t* __restrict__ lo, int n4) {
    int i = blockIdx.x * 256 + threadIdx.x;
    if (i < n4) {
        float4 v = reinterpret_cast<const float4*>(src)[i];
        bf16x4 h, l;
        float f;
        f = v.x; h[0] = (__bf16)f; l[0] = (__bf16)(f - (float)h[0]);
        f = v.y; h[1] = (__bf16)f; l[1] = (__bf16)(f - (float)h[1]);
        f = v.z; h[2] = (__bf16)f; l[2] = (__bf16)(f - (float)h[2]);
        f = v.w; h[3] = (__bf16)f; l[3] = (__bf16)(f - (float)h[3]);
        reinterpret_cast<bf16x4*>(hi)[i] = h;
        reinterpret_cast<bf16x4*>(lo)[i] = l;
    }
}

// ---------------- GEMM: C[m,n] = sum_k A[m,k] * B[n,k] (plain bf16) ----------------
// 128x128 tile, BK=32, 4 waves (2x2), each wave 64x64 out (4x4 frags of 16x16).
// MODE 0: write bf16 row-major [M,N]
// MODE 1: write bf16 transposed per batch-of-2048: Vt[b][n][s], row=b*2048+s
// MODE 2: write fp32 row-major [M,N]
template <int MODE>
__global__ __launch_bounds__(256) void gemm_bt(const bf16_t* __restrict__ A,
                                               const bf16_t* __restrict__ B,
                                               void* __restrict__ Cout,
                                               int M, int N, int K) {
    __shared__ __align__(16) bf16_t As[128 * 32];
    __shared__ __align__(16) bf16_t Bs[128 * 32];
    const int tid = threadIdx.x;
    const int w = tid >> 6, lane = tid & 63;
    const int l15 = lane & 15, g = lane >> 4;
    const int wr = w >> 1, wc = w & 1;
    const int bm = blockIdx.y, bn = blockIdx.x;

    const f32x4 fz = {0.f, 0.f, 0.f, 0.f};
    f32x4 acc[4][4];
#pragma unroll
    for (int m = 0; m < 4; m++)
#pragma unroll
        for (int n = 0; n < 4; n++) acc[m][n] = fz;

    const bf16_t* Ab = A + (size_t)bm * 128 * K;
    const bf16_t* Bb = B + (size_t)bn * 128 * K;
    const int rowL = w * 16 + (lane >> 2);
    const int c8 = (lane & 3) * 8;
    char* AsD = (char*)As + w * 1024;
    char* BsD = (char*)Bs + w * 1024;

    for (int k0 = 0; k0 < K; k0 += 32) {
        g2l16(Ab + (size_t)rowL * K + k0 + c8, AsD);
        g2l16(Ab + (size_t)(rowL + 64) * K + k0 + c8, AsD + 4096);
        g2l16(Bb + (size_t)rowL * K + k0 + c8, BsD);
        g2l16(Bb + (size_t)(rowL + 64) * K + k0 + c8, BsD + 4096);
        __syncthreads();

        bf16x8 af[4], bfr[4];
        const bf16x8* Ap = reinterpret_cast<const bf16x8*>(As + (wr * 64 + l15) * 32 + g * 8);
#pragma unroll
        for (int m = 0; m < 4; m++) af[m] = Ap[m * 64];
        const bf16x8* Bp = reinterpret_cast<const bf16x8*>(Bs + (wc * 64 + l15) * 32 + g * 8);
#pragma unroll
        for (int n = 0; n < 4; n++) bfr[n] = Bp[n * 64];
#pragma unroll
        for (int m = 0; m < 4; m++)
#pragma unroll
            for (int n = 0; n < 4; n++) acc[m][n] = MFMA16(af[m], bfr[n], acc[m][n]);
        __syncthreads();
    }

    const int row0 = bm * 128 + wr * 64 + g * 4;
    const int col0 = bn * 128 + wc * 64 + l15;
#pragma unroll
    for (int m = 0; m < 4; m++)
#pragma unroll
        for (int n = 0; n < 4; n++)
#pragma unroll
            for (int r = 0; r < 4; r++) {
                int row = row0 + m * 16 + r;
                int col = col0 + n * 16;
                float v = acc[m][n][r];
                if (MODE == 0) {
                    ((bf16_t*)Cout)[(size_t)row * N + col] = (__bf16)v;
                } else if (MODE == 1) {
                    int b = row >> 11, s = row & 2047;
                    ((bf16_t*)Cout)[((size_t)b * N + col) * 2048 + s] = (__bf16)v;
                } else {
                    ((float*)Cout)[(size_t)row * N + col] = v;
                }
            }
}

// ---------------- split-pair GEMM: fp32-accurate C = A*B^T via 3 bf16 MFMAs ----------------
// Writes C as (hi, lo) bf16 pair.
__global__ __launch_bounds__(256) void gemm_split(const bf16_t* __restrict__ Ah,
                                                  const bf16_t* __restrict__ Al,
                                                  const bf16_t* __restrict__ Bh,
                                                  const bf16_t* __restrict__ Bl,
                                                  bf16_t* __restrict__ Ch,
                                                  bf16_t* __restrict__ Cl,
                                                  int M, int N, int K) {
    __shared__ __align__(16) bf16_t Ash[128 * 32];
    __shared__ __align__(16) bf16_t Asl[128 * 32];
    __shared__ __align__(16) bf16_t Bsh[128 * 32];
    __shared__ __align__(16) bf16_t Bsl[128 * 32];
    const int tid = threadIdx.x;
    const int w = tid >> 6, lane = tid & 63;
    const int l15 = lane & 15, g = lane >> 4;
    const int wr = w >> 1, wc = w & 1;
    const int bm = blockIdx.y, bn = blockIdx.x;

    const f32x4 fz = {0.f, 0.f, 0.f, 0.f};
    f32x4 acc[4][4];
#pragma unroll
    for (int m = 0; m < 4; m++)
#pragma unroll
        for (int n = 0; n < 4; n++) acc[m][n] = fz;

    const size_t aoff = (size_t)bm * 128 * K;
    const size_t boff = (size_t)bn * 128 * K;
    const int rowL = w * 16 + (lane >> 2);
    const int c8 = (lane & 3) * 8;
    const size_t g0 = (size_t)rowL * K + c8;
    const size_t g1 = (size_t)(rowL + 64) * K + c8;

    for (int k0 = 0; k0 < K; k0 += 32) {
        g2l16(Ah + aoff + g0 + k0, (char*)Ash + w * 1024);
        g2l16(Ah + aoff + g1 + k0, (char*)Ash + w * 1024 + 4096);
        g2l16(Al + aoff + g0 + k0, (char*)Asl + w * 1024);
        g2l16(Al + aoff + g1 + k0, (char*)Asl + w * 1024 + 4096);
        g2l16(Bh + boff + g0 + k0, (char*)Bsh + w * 1024);
        g2l16(Bh + boff + g1 + k0, (char*)Bsh + w * 1024 + 4096);
        g2l16(Bl + boff + g0 + k0, (char*)Bsl + w * 1024);
        g2l16(Bl + boff + g1 + k0, (char*)Bsl + w * 1024 + 4096);
        __syncthreads();

        bf16x8 ah[4], al[4], bh[4], bl[4];
        const int ao = (wr * 64 + l15) * 32 + g * 8;
        const int bo = (wc * 64 + l15) * 32 + g * 8;
#pragma unroll
        for (int m = 0; m < 4; m++) {
            ah[m] = *reinterpret_cast<const bf16x8*>(Ash + ao + m * 512);
            al[m] = *reinterpret_cast<const bf16x8*>(Asl + ao + m * 512);
        }
#pragma unroll
        for (int n = 0; n < 4; n++) {
            bh[n] = *reinterpret_cast<const bf16x8*>(Bsh + bo + n * 512);
            bl[n] = *reinterpret_cast<const bf16x8*>(Bsl + bo + n * 512);
        }
#pragma unroll
        for (int m = 0; m < 4; m++)
#pragma unroll
            for (int n = 0; n < 4; n++) {
                acc[m][n] = MFMA16(ah[m], bh[n], acc[m][n]);
                acc[m][n] = MFMA16(al[m], bh[n], acc[m][n]);
                acc[m][n] = MFMA16(ah[m], bl[n], acc[m][n]);
            }
        __syncthreads();
    }

    const int row0 = bm * 128 + wr * 64 + g * 4;
    const int col0 = bn * 128 + wc * 64 + l15;
#pragma unroll
    for (int m = 0; m < 4; m++)
#pragma unroll
        for (int n = 0; n < 4; n++)
#pragma unroll
            for (int r = 0; r < 4; r++) {
                size_t idx = (size_t)(row0 + m * 16 + r) * N + col0 + n * 16;
                float v = acc[m][n][r];
                bf16_t h = (__bf16)v;
                Ch[idx] = h;
                Cl[idx] = (__bf16)(v - (float)h);
            }
}

// ---------------- causal flash attention (split-pair scores) ----------------
// Qh/Ql,Kh/Kl: bf16 [B*S, 1024] (head h at cols h*64..h*64+63). Vt: bf16 [B][1024][S].
// O: bf16 [B*S, 1024]. Block: (q-tile of 64 rows, h, b); 4 waves x 16 q-rows.
__global__ __launch_bounds__(256) void attn_k(const bf16_t* __restrict__ Qh,
                                              const bf16_t* __restrict__ Ql,
                                              const bf16_t* __restrict__ Kh,
                                              const bf16_t* __restrict__ Kl,
                                              const bf16_t* __restrict__ Vt,
                                              bf16_t* __restrict__ O) {
    const int qt = blockIdx.x, h = blockIdx.y, b = blockIdx.z;
    const int tid = threadIdx.x, w = tid >> 6, lane = tid & 63;
    const int l15 = lane & 15, g = lane >> 4;
    const int qr0 = qt * 64 + w * 16;

    __shared__ __align__(16) bf16_t P[4][16][72];

    const size_t boff = (size_t)b * 2048 * 1024;
    bf16x8 qh[2], ql[2];
#pragma unroll
    for (int t = 0; t < 2; t++) {
        size_t qi = boff + (size_t)(qr0 + l15) * 1024 + h * 64 + t * 32 + g * 8;
        qh[t] = *reinterpret_cast<const bf16x8*>(Qh + qi);
        ql[t] = *reinterpret_cast<const bf16x8*>(Ql + qi);
    }

    const f32x4 fz = {0.f, 0.f, 0.f, 0.f};
    f32x4 oacc[4];
#pragma unroll
    for (int n = 0; n < 4; n++) oacc[n] = fz;
    float mi[4], li[4];
#pragma unroll
    for (int r = 0; r < 4; r++) { mi[r] = -__builtin_inff(); li[r] = 0.f; }

    const bf16_t* Vb0 = Vt + (size_t)b * 1024 * 2048 + (size_t)(h * 64) * 2048;

    for (int t = 0; t <= qt; ++t) {
        const int kv0 = t * 64;
        f32x4 sacc[4];
#pragma unroll
        for (int n = 0; n < 4; n++) sacc[n] = fz;
#pragma unroll
        for (int kk = 0; kk < 2; kk++) {
            const size_t kc = boff + h * 64 + kk * 32 + g * 8;
#pragma unroll
            for (int n = 0; n < 4; n++) {
                size_t ki = kc + (size_t)(kv0 + n * 16 + l15) * 1024;
                bf16x8 khf = *reinterpret_cast<const bf16x8*>(Kh + ki);
                bf16x8 klf = *reinterpret_cast<const bf16x8*>(Kl + ki);
                sacc[n] = MFMA16(qh[kk], khf, sacc[n]);
                sacc[n] = MFMA16(ql[kk], khf, sacc[n]);
                sacc[n] = MFMA16(qh[kk], klf, sacc[n]);
            }
        }
        // scale + causal mask + online softmax. C-layout: row=g*4+r, col=l15 (+16n)
        float sv[4][4], pmax[4];
#pragma unroll
        for (int r = 0; r < 4; r++) pmax[r] = -__builtin_inff();
        const bool diag = (t == qt);
#pragma unroll
        for (int n = 0; n < 4; n++)
#pragma unroll
            for (int r = 0; r < 4; r++) {
                float s = sacc[n][r] * 0.125f;
                if (diag && (kv0 + n * 16 + l15) > (qr0 + g * 4 + r)) s = -__builtin_inff();
                sv[n][r] = s;
                pmax[r] = fmaxf(pmax[r], s);
            }
#pragma unroll
        for (int r = 0; r < 4; r++) {
            float v = pmax[r];
            v = fmaxf(v, __shfl_xor(v, 1)); v = fmaxf(v, __shfl_xor(v, 2));
            v = fmaxf(v, __shfl_xor(v, 4)); v = fmaxf(v, __shfl_xor(v, 8));
            pmax[r] = v;
        }
        float alpha[4];
#pragma unroll
        for (int r = 0; r < 4; r++) {
            float mn = fmaxf(mi[r], pmax[r]);
            alpha[r] = __expf(mi[r] - mn);
            mi[r] = mn;
        }
        float rs[4] = {0.f, 0.f, 0.f, 0.f};
#pragma unroll
        for (int n = 0; n < 4; n++)
#pragma unroll
            for (int r = 0; r < 4; r++) {
                float p = __expf(sv[n][r] - mi[r]);
                sv[n][r] = p;
                rs[r] += p;
            }
#pragma unroll
        for (int r = 0; r < 4; r++) {
            float v = rs[r];
            v += __shfl_xor(v, 1); v += __shfl_xor(v, 2);
            v += __shfl_xor(v, 4); v += __shfl_xor(v, 8);
            li[r] = li[r] * alpha[r] + v;
        }
        f32x4 a4 = {alpha[0], alpha[1], alpha[2], alpha[3]};
#pragma unroll
        for (int n = 0; n < 4; n++) oacc[n] *= a4;

        // P -> LDS (true positions), then consume as A-fragment
#pragma unroll
        for (int n = 0; n < 4; n++)
#pragma unroll
            for (int r = 0; r < 4; r++)
                P[w][g * 4 + r][n * 16 + l15] = (__bf16)sv[n][r];
        asm volatile("s_waitcnt lgkmcnt(0)" ::: "memory");
#pragma unroll
        for (int kk = 0; kk < 2; kk++) {
            bf16x8 pa = *reinterpret_cast<const bf16x8*>(&P[w][l15][kk * 32 + g * 8]);
            const bf16_t* Vb = Vb0 + kv0 + kk * 32 + g * 8;
#pragma unroll
            for (int n = 0; n < 4; n++) {
                bf16x8 vf = *reinterpret_cast<const bf16x8*>(Vb + (size_t)(n * 16 + l15) * 2048);
                oacc[n] = MFMA16(pa, vf, oacc[n]);
            }
        }
    }
    float inv[4];
#pragma unroll
    for (int r = 0; r < 4; r++) inv[r] = 1.f / li[r];
#pragma unroll
    for (int n = 0; n < 4; n++)
#pragma unroll
        for (int r = 0; r < 4; r++)
            O[boff + (size_t)(qr0 + g * 4 + r) * 1024 + h * 64 + n * 16 + l15] =
                (__bf16)(oacc[n][r] * inv[r]);
}

extern "C" void kernel_launch(void* const* d_in, const int* in_sizes, int n_in,
                              void* d_out, int out_size, void* d_ws, size_t ws_size,
                              hipStream_t stream) {
    const float* x  = (const float*)d_in[0];
    const float* Wq = (const float*)d_in[1];
    const float* Wk = (const float*)d_in[2];
    const float* Wv = (const float*)d_in[3];
    const float* Wo = (const float*)d_in[4];

    char* ws = (char*)d_ws;
    const size_t MB = (size_t)1 << 20;
    bf16_t* xh  = (bf16_t*)(ws);
    bf16_t* xl  = (bf16_t*)(ws + 16 * MB);
    bf16_t* Qh  = (bf16_t*)(ws + 32 * MB);
    bf16_t* Ql  = (bf16_t*)(ws + 48 * MB);
    bf16_t* Kh  = (bf16_t*)(ws + 64 * MB);
    bf16_t* Kl  = (bf16_t*)(ws + 80 * MB);
    bf16_t* Vt  = (bf16_t*)(ws + 96 * MB);
    bf16_t* Ob  = (bf16_t*)(ws + 112 * MB);
    bf16_t* Wqh = (bf16_t*)(ws + 128 * MB);
    bf16_t* Wql = (bf16_t*)(ws + 130 * MB);
    bf16_t* Wkh = (bf16_t*)(ws + 132 * MB);
    bf16_t* Wkl = (bf16_t*)(ws + 134 * MB);
    bf16_t* Wvh = (bf16_t*)(ws + 136 * MB);
    bf16_t* Woh = (bf16_t*)(ws + 138 * MB);

    // conversions / splits.  x: 8,388,608 floats = 2,097,152 float4.
    // W*: 1,048,576 floats = 262,144 float4 -> grid 1024 x 256.
    cvt_split_k<<<8192, 256, 0, stream>>>(x, xh, xl, 2097152);
    cvt_split_k<<<1024, 256, 0, stream>>>(Wq, Wqh, Wql, 262144);
    cvt_split_k<<<1024, 256, 0, stream>>>(Wk, Wkh, Wkl, 262144);
    cvt_f32_bf16_k<<<1024, 256, 0, stream>>>(Wv, Wvh, 262144);
    cvt_f32_bf16_k<<<1024, 256, 0, stream>>>(Wo, Woh, 262144);

    // projections
    dim3 gp(1024 / 128, 8192 / 128);
    gemm_split<<<gp, 256, 0, stream>>>(xh, xl, Wqh, Wql, Qh, Ql, 8192, 1024, 1024);
    gemm_split<<<gp, 256, 0, stream>>>(xh, xl, Wkh, Wkl, Kh, Kl, 8192, 1024, 1024);
    gemm_bt<1><<<gp, 256, 0, stream>>>(xh, Wvh, Vt, 8192, 1024, 1024);

    // attention
    attn_k<<<dim3(32, 16, 4), 256, 0, stream>>>(Qh, Ql, Kh, Kl, Vt, Ob);

    // output projection (fp32 epilogue to d_out)
    gemm_bt<2><<<gp, 256, 0, stream>>>(Ob, Woh, d_out, 8192, 1024, 1024);
}

// Round 4
// 454.967 us; speedup vs baseline: 2.0398x; 2.0398x over previous
//
#include <hip/hip_runtime.h>
#include <hip/hip_bf16.h>

typedef __bf16 bf16_t;
typedef __bf16 bf16x4 __attribute__((ext_vector_type(4)));
typedef __bf16 bf16x8 __attribute__((ext_vector_type(8)));
typedef float f32x4 __attribute__((ext_vector_type(4)));

#define MFMA16(a, b, c) __builtin_amdgcn_mfma_f32_16x16x32_bf16((a), (b), (c), 0, 0, 0)

__device__ inline void g2l16(const void* g, void* l) {
    __builtin_amdgcn_global_load_lds((const __attribute__((address_space(1))) void*)g,
                                     (__attribute__((address_space(3))) void*)l, 16, 0, 0);
}

// ---------------- fp32 -> bf16 conversion (vectorized) ----------------
__global__ __launch_bounds__(256) void cvt_f32_bf16_k(const float* __restrict__ src,
                                                      bf16_t* __restrict__ dst, int n4) {
    int i = blockIdx.x * 256 + threadIdx.x;
    if (i < n4) {
        float4 v = reinterpret_cast<const float4*>(src)[i];
        bf16x4 o;
        o[0] = (__bf16)v.x; o[1] = (__bf16)v.y; o[2] = (__bf16)v.z; o[3] = (__bf16)v.w;
        reinterpret_cast<bf16x4*>(dst)[i] = o;
    }
}

// ---------------- fp32 -> (hi, lo) bf16 pair split ----------------
__global__ __launch_bounds__(256) void cvt_split_k(const float* __restrict__ src,
                                                   bf16_t* __restrict__ hi,
                                                   bf16_t* __restrict__ lo, int n4) {
    int i = blockIdx.x * 256 + threadIdx.x;
    if (i < n4) {
        float4 v = reinterpret_cast<const float4*>(src)[i];
        bf16x4 h, l;
        float f;
        f = v.x; h[0] = (__bf16)f; l[0] = (__bf16)(f - (float)h[0]);
        f = v.y; h[1] = (__bf16)f; l[1] = (__bf16)(f - (float)h[1]);
        f = v.z; h[2] = (__bf16)f; l[2] = (__bf16)(f - (float)h[2]);
        f = v.w; h[3] = (__bf16)f; l[3] = (__bf16)(f - (float)h[3]);
        reinterpret_cast<bf16x4*>(hi)[i] = h;
        reinterpret_cast<bf16x4*>(lo)[i] = l;
    }
}

// ---------------- GEMM: C[m,n] = sum_k A[m,k] * B[n,k] (plain bf16) ----------------
template <int MODE>
__global__ __launch_bounds__(256) void gemm_bt(const bf16_t* __restrict__ A,
                                               const bf16_t* __restrict__ B,
                                               void* __restrict__ Cout,
                                               int M, int N, int K) {
    __shared__ __align__(16) bf16_t As[128 * 32];
    __shared__ __align__(16) bf16_t Bs[128 * 32];
    const int tid = threadIdx.x;
    const int w = tid >> 6, lane = tid & 63;
    const int l15 = lane & 15, g = lane >> 4;
    const int wr = w >> 1, wc = w & 1;
    const int bm = blockIdx.y, bn = blockIdx.x;

    const f32x4 fz = {0.f, 0.f, 0.f, 0.f};
    f32x4 acc[4][4];
#pragma unroll
    for (int m = 0; m < 4; m++)
#pragma unroll
        for (int n = 0; n < 4; n++) acc[m][n] = fz;

    const bf16_t* Ab = A + (size_t)bm * 128 * K;
    const bf16_t* Bb = B + (size_t)bn * 128 * K;
    const int rowL = w * 16 + (lane >> 2);
    const int c8 = (lane & 3) * 8;
    char* AsD = (char*)As + w * 1024;
    char* BsD = (char*)Bs + w * 1024;

    for (int k0 = 0; k0 < K; k0 += 32) {
        g2l16(Ab + (size_t)rowL * K + k0 + c8, AsD);
        g2l16(Ab + (size_t)(rowL + 64) * K + k0 + c8, AsD + 4096);
        g2l16(Bb + (size_t)rowL * K + k0 + c8, BsD);
        g2l16(Bb + (size_t)(rowL + 64) * K + k0 + c8, BsD + 4096);
        __syncthreads();

        bf16x8 af[4], bfr[4];
        const bf16x8* Ap = reinterpret_cast<const bf16x8*>(As + (wr * 64 + l15) * 32 + g * 8);
#pragma unroll
        for (int m = 0; m < 4; m++) af[m] = Ap[m * 64];
        const bf16x8* Bp = reinterpret_cast<const bf16x8*>(Bs + (wc * 64 + l15) * 32 + g * 8);
#pragma unroll
        for (int n = 0; n < 4; n++) bfr[n] = Bp[n * 64];
#pragma unroll
        for (int m = 0; m < 4; m++)
#pragma unroll
            for (int n = 0; n < 4; n++) acc[m][n] = MFMA16(af[m], bfr[n], acc[m][n]);
        __syncthreads();
    }

    const int row0 = bm * 128 + wr * 64 + g * 4;
    const int col0 = bn * 128 + wc * 64 + l15;
#pragma unroll
    for (int m = 0; m < 4; m++)
#pragma unroll
        for (int n = 0; n < 4; n++)
#pragma unroll
            for (int r = 0; r < 4; r++) {
                int row = row0 + m * 16 + r;
                int col = col0 + n * 16;
                float v = acc[m][n][r];
                if (MODE == 0) {
                    ((bf16_t*)Cout)[(size_t)row * N + col] = (__bf16)v;
                } else if (MODE == 1) {
                    int b = row >> 11, s = row & 2047;
                    ((bf16_t*)Cout)[((size_t)b * N + col) * 2048 + s] = (__bf16)v;
                } else {
                    ((float*)Cout)[(size_t)row * N + col] = v;
                }
            }
}

// ---------------- split-pair GEMM: fp32-accurate C = A*B^T via 3 bf16 MFMAs ----------------
__global__ __launch_bounds__(256) void gemm_split(const bf16_t* __restrict__ Ah,
                                                  const bf16_t* __restrict__ Al,
                                                  const bf16_t* __restrict__ Bh,
                                                  const bf16_t* __restrict__ Bl,
                                                  bf16_t* __restrict__ Ch,
                                                  bf16_t* __restrict__ Cl,
                                                  int M, int N, int K) {
    __shared__ __align__(16) bf16_t Ash[128 * 32];
    __shared__ __align__(16) bf16_t Asl[128 * 32];
    __shared__ __align__(16) bf16_t Bsh[128 * 32];
    __shared__ __align__(16) bf16_t Bsl[128 * 32];
    const int tid = threadIdx.x;
    const int w = tid >> 6, lane = tid & 63;
    const int l15 = lane & 15, g = lane >> 4;
    const int wr = w >> 1, wc = w & 1;
    const int bm = blockIdx.y, bn = blockIdx.x;

    const f32x4 fz = {0.f, 0.f, 0.f, 0.f};
    f32x4 acc[4][4];
#pragma unroll
    for (int m = 0; m < 4; m++)
#pragma unroll
        for (int n = 0; n < 4; n++) acc[m][n] = fz;

    const size_t aoff = (size_t)bm * 128 * K;
    const size_t boff = (size_t)bn * 128 * K;
    const int rowL = w * 16 + (lane >> 2);
    const int c8 = (lane & 3) * 8;
    const size_t g0 = (size_t)rowL * K + c8;
    const size_t g1 = (size_t)(rowL + 64) * K + c8;

    for (int k0 = 0; k0 < K; k0 += 32) {
        g2l16(Ah + aoff + g0 + k0, (char*)Ash + w * 1024);
        g2l16(Ah + aoff + g1 + k0, (char*)Ash + w * 1024 + 4096);
        g2l16(Al + aoff + g0 + k0, (char*)Asl + w * 1024);
        g2l16(Al + aoff + g1 + k0, (char*)Asl + w * 1024 + 4096);
        g2l16(Bh + boff + g0 + k0, (char*)Bsh + w * 1024);
        g2l16(Bh + boff + g1 + k0, (char*)Bsh + w * 1024 + 4096);
        g2l16(Bl + boff + g0 + k0, (char*)Bsl + w * 1024);
        g2l16(Bl + boff + g1 + k0, (char*)Bsl + w * 1024 + 4096);
        __syncthreads();

        bf16x8 ah[4], al[4], bh[4], bl[4];
        const int ao = (wr * 64 + l15) * 32 + g * 8;
        const int bo = (wc * 64 + l15) * 32 + g * 8;
#pragma unroll
        for (int m = 0; m < 4; m++) {
            ah[m] = *reinterpret_cast<const bf16x8*>(Ash + ao + m * 512);
            al[m] = *reinterpret_cast<const bf16x8*>(Asl + ao + m * 512);
        }
#pragma unroll
        for (int n = 0; n < 4; n++) {
            bh[n] = *reinterpret_cast<const bf16x8*>(Bsh + bo + n * 512);
            bl[n] = *reinterpret_cast<const bf16x8*>(Bsl + bo + n * 512);
        }
#pragma unroll
        for (int m = 0; m < 4; m++)
#pragma unroll
            for (int n = 0; n < 4; n++) {
                acc[m][n] = MFMA16(ah[m], bh[n], acc[m][n]);
                acc[m][n] = MFMA16(al[m], bh[n], acc[m][n]);
                acc[m][n] = MFMA16(ah[m], bl[n], acc[m][n]);
            }
        __syncthreads();
    }

    const int row0 = bm * 128 + wr * 64 + g * 4;
    const int col0 = bn * 128 + wc * 64 + l15;
#pragma unroll
    for (int m = 0; m < 4; m++)
#pragma unroll
        for (int n = 0; n < 4; n++)
#pragma unroll
            for (int r = 0; r < 4; r++) {
                size_t idx = (size_t)(row0 + m * 16 + r) * N + col0 + n * 16;
                float v = acc[m][n][r];
                bf16_t h = (__bf16)v;
                Ch[idx] = h;
                Cl[idx] = (__bf16)(v - (float)h);
            }
}

// ---------------- causal flash attention, LDS-staged K/V, double-buffered ----------------
// Block: 128 Q-rows x one (h,b). 4 waves x 32 rows. KV-tile = 64.
// Kh/Kl/V tiles staged via global_load_lds with XOR-swizzle (chunk ^= row&7, 16B chunks):
// linear LDS dest + inverse-swizzled per-lane global source; swizzled ds_read.
__global__ __launch_bounds__(256) void attn_k(const bf16_t* __restrict__ Qh,
                                              const bf16_t* __restrict__ Ql,
                                              const bf16_t* __restrict__ Kh,
                                              const bf16_t* __restrict__ Kl,
                                              const bf16_t* __restrict__ Vt,
                                              bf16_t* __restrict__ O) {
    const int qt = (int)gridDim.x - 1 - (int)blockIdx.x;   // longest blocks first
    const int h = blockIdx.y, b = blockIdx.z;
    const int tid = threadIdx.x, w = tid >> 6, lane = tid & 63;
    const int l15 = lane & 15, g = lane >> 4;
    const int qrw = qt * 128 + w * 32;                     // wave's first q row

    __shared__ __align__(16) bf16_t Ks[2][4096];   // K hi tile  [kv=64][d=64]
    __shared__ __align__(16) bf16_t Ls[2][4096];   // K lo tile
    __shared__ __align__(16) bf16_t Vs[2][4096];   // V^T tile   [v=64][kv=64]
    __shared__ __align__(16) bf16_t Ps[4][2048];   // per-wave P [q=32][kv=64]

    const size_t boff = (size_t)b * 2048 * 1024;
    const size_t vbase = (size_t)b * 1024 * 2048 + (size_t)(h * 64) * 2048;

    // Q fragments (hi/lo), rows qrw + m*16 + l15
    bf16x8 qh[2][2], ql[2][2];
#pragma unroll
    for (int m = 0; m < 2; m++)
#pragma unroll
        for (int kk = 0; kk < 2; kk++) {
            size_t qi = boff + (size_t)(qrw + m * 16 + l15) * 1024 + h * 64 + kk * 32 + g * 8;
            qh[m][kk] = *reinterpret_cast<const bf16x8*>(Qh + qi);
            ql[m][kk] = *reinterpret_cast<const bf16x8*>(Ql + qi);
        }

    // staging lane decomposition: lane covers (row += lane>>3, chunk = lane&7)
    const int li8 = lane >> 3, lc8 = lane & 7;
    const int csrc = (lc8 ^ li8);   // inverse-swizzled source chunk (16B units)

    const f32x4 fz = {0.f, 0.f, 0.f, 0.f};
    f32x4 oacc[2][4];
#pragma unroll
    for (int m = 0; m < 2; m++)
#pragma unroll
        for (int n = 0; n < 4; n++) oacc[m][n] = fz;
    float mst[2][4], lst[2][4];
#pragma unroll
    for (int m = 0; m < 2; m++)
#pragma unroll
        for (int r = 0; r < 4; r++) { mst[m][r] = -__builtin_inff(); lst[m][r] = 0.f; }

#define STAGE(T, BUF)                                                                    \
    do {                                                                                 \
        const int kv0_ = (T) * 64;                                                       \
        _Pragma("unroll")                                                                \
        for (int jj = 0; jj < 2; jj++) {                                                 \
            const int j = w * 2 + jj;                                                    \
            const size_t kr = boff + (size_t)(kv0_ + j * 8 + li8) * 1024 + h * 64 + csrc * 8; \
            g2l16(Kh + kr, (char*)Ks[BUF] + j * 1024);                                   \
            g2l16(Kl + kr, (char*)Ls[BUF] + j * 1024);                                   \
            const size_t vr = vbase + (size_t)(j * 8 + li8) * 2048 + kv0_ + csrc * 8;    \
            g2l16(Vt + vr, (char*)Vs[BUF] + j * 1024);                                   \
        }                                                                                \
    } while (0)

    const int nt = 2 * qt + 2;
    STAGE(0, 0);
    __syncthreads();

    for (int t = 0; t < nt; ++t) {
        const int buf = t & 1;
        if (t + 1 < nt) STAGE(t + 1, buf ^ 1);   // prefetch overlaps compute; drained at barrier
        const int kv0 = t * 64;

        if (kv0 <= qrw + 31) {   // wave-uniform: skip fully-masked tiles
            // ---- QK^T (split precision: 3 MFMAs) ----
            f32x4 sacc[2][4];
#pragma unroll
            for (int m = 0; m < 2; m++)
#pragma unroll
                for (int n = 0; n < 4; n++) sacc[m][n] = fz;
#pragma unroll
            for (int kk = 0; kk < 2; kk++)
#pragma unroll
                for (int n = 0; n < 4; n++) {
                    const int off = (n * 16 + l15) * 64 + (((kk * 4 + g) ^ (l15 & 7)) << 3);
                    bf16x8 khf = *reinterpret_cast<const bf16x8*>(&Ks[buf][off]);
                    bf16x8 klf = *reinterpret_cast<const bf16x8*>(&Ls[buf][off]);
#pragma unroll
                    for (int m = 0; m < 2; m++) {
                        sacc[m][n] = MFMA16(qh[m][kk], khf, sacc[m][n]);
                        sacc[m][n] = MFMA16(ql[m][kk], khf, sacc[m][n]);
                        sacc[m][n] = MFMA16(qh[m][kk], klf, sacc[m][n]);
                    }
                }

            // ---- online softmax per row-fragment ----
            const bool diag = (kv0 + 63 > qrw);
#pragma unroll
            for (int m = 0; m < 2; m++) {
                float sv[4][4], pmax[4];
#pragma unroll
                for (int r = 0; r < 4; r++) pmax[r] = -__builtin_inff();
#pragma unroll
                for (int n = 0; n < 4; n++)
#pragma unroll
                    for (int r = 0; r < 4; r++) {
                        float s = sacc[m][n][r] * 0.125f;
                        if (diag && (kv0 + n * 16 + l15) > (qrw + m * 16 + g * 4 + r))
                            s = -__builtin_inff();
                        sv[n][r] = s;
                        pmax[r] = fmaxf(pmax[r], s);
                    }
#pragma unroll
                for (int r = 0; r < 4; r++) {
                    float v = pmax[r];
                    v = fmaxf(v, __shfl_xor(v, 1)); v = fmaxf(v, __shfl_xor(v, 2));
                    v = fmaxf(v, __shfl_xor(v, 4)); v = fmaxf(v, __shfl_xor(v, 8));
                    pmax[r] = v;
                }
                float alpha[4];
#pragma unroll
                for (int r = 0; r < 4; r++) {
                    float mn = fmaxf(mst[m][r], pmax[r]);
                    alpha[r] = __expf(mst[m][r] - mn);
                    mst[m][r] = mn;
                }
                float rs[4] = {0.f, 0.f, 0.f, 0.f};
#pragma unroll
                for (int n = 0; n < 4; n++)
#pragma unroll
                    for (int r = 0; r < 4; r++) {
                        float p = __expf(sv[n][r] - mst[m][r]);
                        sv[n][r] = p;
                        rs[r] += p;
                    }
#pragma unroll
                for (int r = 0; r < 4; r++) {
                    float v = rs[r];
                    v += __shfl_xor(v, 1); v += __shfl_xor(v, 2);
                    v += __shfl_xor(v, 4); v += __shfl_xor(v, 8);
                    lst[m][r] = lst[m][r] * alpha[r] + v;
                }
                f32x4 a4 = {alpha[0], alpha[1], alpha[2], alpha[3]};
#pragma unroll
                for (int n = 0; n < 4; n++) oacc[m][n] *= a4;

                // P -> LDS (XOR-swizzled: chunk ^= row&7)
#pragma unroll
                for (int n = 0; n < 4; n++)
#pragma unroll
                    for (int r = 0; r < 4; r++) {
                        const int row = m * 16 + g * 4 + r;
                        const int col = n * 16 + l15;
                        const int idx = row * 64 + ((((col >> 3) ^ (row & 7))) << 3) + (col & 7);
                        Ps[w][idx] = (__bf16)sv[n][r];
                    }
            }

            asm volatile("s_waitcnt lgkmcnt(0)" ::: "memory");
            __builtin_amdgcn_sched_barrier(0);

            // ---- PV ----
#pragma unroll
            for (int kk = 0; kk < 2; kk++) {
                bf16x8 pa[2];
#pragma unroll
                for (int m = 0; m < 2; m++) {
                    const int prow = m * 16 + l15;
                    pa[m] = *reinterpret_cast<const bf16x8*>(
                        &Ps[w][prow * 64 + (((kk * 4 + g) ^ (l15 & 7)) << 3)]);
                }
#pragma unroll
                for (int n = 0; n < 4; n++) {
                    const int voff = (n * 16 + l15) * 64 + (((kk * 4 + g) ^ (l15 & 7)) << 3);
                    bf16x8 vf = *reinterpret_cast<const bf16x8*>(&Vs[buf][voff]);
#pragma unroll
                    for (int m = 0; m < 2; m++) oacc[m][n] = MFMA16(pa[m], vf, oacc[m][n]);
                }
            }
        }
        __syncthreads();   // drains prefetch vmcnt + lgkm; read-done for buf
    }
#undef STAGE

    // ---- epilogue ----
#pragma unroll
    for (int m = 0; m < 2; m++) {
        float inv[4];
#pragma unroll
        for (int r = 0; r < 4; r++) inv[r] = 1.f / lst[m][r];
#pragma unroll
        for (int n = 0; n < 4; n++)
#pragma unroll
            for (int r = 0; r < 4; r++)
                O[boff + (size_t)(qrw + m * 16 + g * 4 + r) * 1024 + h * 64 + n * 16 + l15] =
                    (__bf16)(oacc[m][n][r] * inv[r]);
    }
}

extern "C" void kernel_launch(void* const* d_in, const int* in_sizes, int n_in,
                              void* d_out, int out_size, void* d_ws, size_t ws_size,
                              hipStream_t stream) {
    const float* x  = (const float*)d_in[0];
    const float* Wq = (const float*)d_in[1];
    const float* Wk = (const float*)d_in[2];
    const float* Wv = (const float*)d_in[3];
    const float* Wo = (const float*)d_in[4];

    char* ws = (char*)d_ws;
    const size_t MB = (size_t)1 << 20;
    bf16_t* xh  = (bf16_t*)(ws);
    bf16_t* xl  = (bf16_t*)(ws + 16 * MB);
    bf16_t* Qh  = (bf16_t*)(ws + 32 * MB);
    bf16_t* Ql  = (bf16_t*)(ws + 48 * MB);
    bf16_t* Kh  = (bf16_t*)(ws + 64 * MB);
    bf16_t* Kl  = (bf16_t*)(ws + 80 * MB);
    bf16_t* Vt  = (bf16_t*)(ws + 96 * MB);
    bf16_t* Ob  = (bf16_t*)(ws + 112 * MB);
    bf16_t* Wqh = (bf16_t*)(ws + 128 * MB);
    bf16_t* Wql = (bf16_t*)(ws + 130 * MB);
    bf16_t* Wkh = (bf16_t*)(ws + 132 * MB);
    bf16_t* Wkl = (bf16_t*)(ws + 134 * MB);
    bf16_t* Wvh = (bf16_t*)(ws + 136 * MB);
    bf16_t* Woh = (bf16_t*)(ws + 138 * MB);

    // conversions / splits.  x: 2,097,152 float4; W*: 262,144 float4.
    cvt_split_k<<<8192, 256, 0, stream>>>(x, xh, xl, 2097152);
    cvt_split_k<<<1024, 256, 0, stream>>>(Wq, Wqh, Wql, 262144);
    cvt_split_k<<<1024, 256, 0, stream>>>(Wk, Wkh, Wkl, 262144);
    cvt_f32_bf16_k<<<1024, 256, 0, stream>>>(Wv, Wvh, 262144);
    cvt_f32_bf16_k<<<1024, 256, 0, stream>>>(Wo, Woh, 262144);

    // projections
    dim3 gp(1024 / 128, 8192 / 128);
    gemm_split<<<gp, 256, 0, stream>>>(xh, xl, Wqh, Wql, Qh, Ql, 8192, 1024, 1024);
    gemm_split<<<gp, 256, 0, stream>>>(xh, xl, Wkh, Wkl, Kh, Kl, 8192, 1024, 1024);
    gemm_bt<1><<<gp, 256, 0, stream>>>(xh, Wvh, Vt, 8192, 1024, 1024);

    // attention: 16 q-tiles of 128 x 16 heads x 4 batches
    attn_k<<<dim3(16, 16, 4), 256, 0, stream>>>(Qh, Ql, Kh, Kl, Vt, Ob);

    // output projection (fp32 epilogue to d_out)
    gemm_bt<2><<<gp, 256, 0, stream>>>(Ob, Woh, d_out, 8192, 1024, 1024);
}